// Round 4
// baseline (1582.224 us; speedup 1.0000x reference)
//
#include <hip/hip_runtime.h>
#include <math.h>

// FastLearnableEMA: y[b,t,c] = cumsum_t(x * w) / max(a^t, 1e-8)
//   a = clamp(sigmoid(logit_alpha), 1e-4, 1-1e-4)      [C]
//   w[t] = a^t * (t==0 ? 1 : (1-a))
// B=32, T=2048, C=512, fp32. HBM floor = 268 MB (~43 us @ 6.3 TB/s).
//
// Single-kernel decoupled-lookback scan (StreamScan style):
//  - chunk = 32 t-steps x 256 channels; 4096 blocks x 256 thr; 1 ch/thread;
//    the chunk's x values live in 32 VGPRs -> x read from HBM exactly once.
//  - block rank via atomic ticket (= scheduling order => predecessors always
//    running-or-done => deadlock-free despite undefined dispatch order).
//  - backward lookback, flags: 1=aggregate ready, 2=inclusive prefix ready.
//    Device-scope acquire/release for cross-XCD visibility.

#define B_   32
#define T_   2048
#define C_   512
#define TB   32
#define NTB  (T_ / TB)            // 64 chunks per chain
#define NCH  (B_ * (C_ / 256))    // 64 chains (b x channel-half)
#define CPB  256                  // channels per block
#define NBLK (NTB * NCH)          // 4096 blocks

__device__ __forceinline__ float clamp_sig(float z) {
    float a = 1.0f / (1.0f + expf(-z));
    return fminf(fmaxf(a, 1e-4f), 1.0f - 1e-4f);
}

__global__ __launch_bounds__(256, 4)
void ema_fused(const float* __restrict__ x, const float* __restrict__ la,
               float* __restrict__ y, int* __restrict__ ticket,
               int* __restrict__ flags, float* __restrict__ agg,
               float* __restrict__ pref) {
    __shared__ int s_rank;
    __shared__ int s_flag;
    const int tid = threadIdx.x;
    if (tid == 0) s_rank = atomicAdd(ticket, 1);
    __syncthreads();
    const int rank  = s_rank;
    const int tb    = rank >> 6;          // rank = tb*NCH + chain: all chains'
    const int chain = rank & (NCH - 1);   // chunk k ticket before chunk k+1
    const int b     = chain >> 1;
    const int c     = ((chain & 1) << 8) + tid;
    const int t0    = tb * TB;
    const int myidx = chain * NTB + tb;

    const float a   = clamp_sig(la[c]);
    const float oma = 1.0f - a;
    const float l2a = log2f(a);
    const float ap0 = exp2f((float)t0 * l2a);   // a^t0 (underflow->0 ok)

    // ---- load chunk into registers (32 independent dword loads) + local sum
    const float* __restrict__ xp = x + ((size_t)b * T_ + t0) * C_ + c;
    float xr[TB];
    #pragma unroll
    for (int i = 0; i < TB; ++i) xr[i] = xp[(size_t)i * C_];

    float ap = ap0;
    float s  = 0.0f;
    #pragma unroll
    for (int i = 0; i < TB; ++i) {
        const float w = (t0 + i == 0) ? 1.0f : ap * oma;
        s = fmaf(xr[i], w, s);
        ap *= a;
    }

    // ---- publish aggregate
    agg[(size_t)myidx * CPB + tid] = s;
    __threadfence();
    __syncthreads();
    if (tid == 0)
        __hip_atomic_store(&flags[myidx], 1, __ATOMIC_RELEASE,
                           __HIP_MEMORY_SCOPE_AGENT);

    // ---- backward decoupled lookback
    float Se = 0.0f;
    int q = tb - 1;
    while (q >= 0) {
        if (tid == 0) {
            int f;
            do {
                f = __hip_atomic_load(&flags[chain * NTB + q],
                                      __ATOMIC_ACQUIRE,
                                      __HIP_MEMORY_SCOPE_AGENT);
                if (f == 0) __builtin_amdgcn_s_sleep(8);
            } while (f == 0);
            s_flag = f;
        }
        __syncthreads();
        const int f = s_flag;
        if (f == 2) Se += pref[(size_t)(chain * NTB + q) * CPB + tid];
        else        Se += agg [(size_t)(chain * NTB + q) * CPB + tid];
        __syncthreads();   // protect s_flag before next overwrite
        if (f == 2) break;
        --q;
    }

    // ---- publish inclusive prefix (unblocks successors before we emit)
    pref[(size_t)myidx * CPB + tid] = Se + s;
    __threadfence();
    __syncthreads();
    if (tid == 0)
        __hip_atomic_store(&flags[myidx], 2, __ATOMIC_RELEASE,
                           __HIP_MEMORY_SCOPE_AGENT);

    // ---- phase 2: replay from registers, emit y
    // 1/max(a^t,1e-8) == min(a^-t, 1e8); inf clamps to 1e8 (matches EPS)
    float S     = Se;
    float apw   = ap0;
    float invap = exp2f(-(float)t0 * l2a);
    const float inva = 1.0f / a;
    float* __restrict__ yp = y + ((size_t)b * T_ + t0) * C_ + c;
    #pragma unroll
    for (int i = 0; i < TB; ++i) {
        const float w = (t0 + i == 0) ? 1.0f : apw * oma;
        S = fmaf(xr[i], w, S);
        __builtin_nontemporal_store(S * fminf(invap, 1e8f),
                                    yp + (size_t)i * C_);
        apw   *= a;
        invap *= inva;
    }
}

extern "C" void kernel_launch(void* const* d_in, const int* in_sizes, int n_in,
                              void* d_out, int out_size, void* d_ws, size_t ws_size,
                              hipStream_t stream) {
    const float* x  = (const float*)d_in[0];   // [32, 2048, 512] fp32
    const float* la = (const float*)d_in[1];   // [512] fp32
    float* y = (float*)d_out;                  // [32, 2048, 512] fp32

    // ws layout: [0] ticket | [256] flags[NCH*NTB] | [32K] agg 4MB | [32K+4M] pref 4MB
    int*   ticket = (int*)d_ws;
    int*   flags  = (int*)((char*)d_ws + 256);
    float* agg    = (float*)((char*)d_ws + (32 << 10));
    float* pref   = (float*)((char*)d_ws + (32 << 10) + (4 << 20));

    // zero ticket + flags (captured as a memset node)
    hipMemsetAsync(d_ws, 0, 32 << 10, stream);

    hipLaunchKernelGGL(ema_fused, dim3(NBLK), dim3(CPB), 0, stream,
                       x, la, y, ticket, flags, agg, pref);
}

// Round 5
// 255.577 us; speedup vs baseline: 6.1908x; 6.1908x over previous
//
#include <hip/hip_runtime.h>
#include <math.h>

// FastLearnableEMA: y[b,t,c] = cumsum_t(x * w) / max(a^t, 1e-8)
//   a = clamp(sigmoid(logit_alpha), 1e-4, 1-1e-4)      [C]
//   w[t] = a^t * (t==0 ? 1 : (1-a))
// B=32, T=2048, C=512, fp32. HBM floor = 268 MB (~43 us @ 6.3 TB/s).
//
// 3-kernel hierarchical scan (no serial prologues, no cross-block sync):
//  K1 partials: 1024 blk x 256 thr; thread = 4ch (float4) x 32 t-steps;
//     per-chunk weighted sums (global-weight space) -> ws [B][64][C] (4 MB).
//  K2 scan: 16384 threads; each owns one (b,c) column of ws, fully-unrolled
//     64-elt exclusive scan in place (L2-resident).
//  K3 apply: same shape as K1; reads ONE exclusive-prefix float4, re-streams
//     x (hits Infinity Cache - verified R1: FETCH 127MB despite double read),
//     nontemporal-stores y.

#define B_   32
#define T_   2048
#define C_   512
#define TB   32
#define NTB  (T_ / TB)   // 64 chunks

typedef float f32x4 __attribute__((ext_vector_type(4)));

__device__ __forceinline__ float clamp_sig(float z) {
    float a = 1.0f / (1.0f + expf(-z));
    return fminf(fmaxf(a, 1e-4f), 1.0f - 1e-4f);
}

// block: 256 thr = 2 t-chunks x 128 ch-threads (512 ch via float4)
// grid: 32 b x 32 chunk-pairs = 1024 blocks
__global__ __launch_bounds__(256, 4)
void ema_partials(const float* __restrict__ x,
                  const float* __restrict__ la,
                  float* __restrict__ ws) {
    const int tid = threadIdx.x;
    const int ct  = tid & 127;             // channel-thread
    const int cs  = tid >> 7;              // chunk select (0/1)
    const int b   = blockIdx.x >> 5;
    const int pr  = blockIdx.x & 31;
    const int tb  = (pr << 1) | cs;
    const int c0  = ct << 2;
    const int t0  = tb * TB;

    const float4 z4 = *(const float4*)(la + c0);
    const float zz[4] = {z4.x, z4.y, z4.z, z4.w};
    float a[4], oma[4], ap[4];
    #pragma unroll
    for (int j = 0; j < 4; ++j) {
        a[j]   = clamp_sig(zz[j]);
        oma[j] = 1.0f - a[j];
        ap[j]  = exp2f((float)t0 * log2f(a[j]));   // a^t0 (underflow->0 ok)
    }

    const float4* __restrict__ xp =
        (const float4*)(x + ((size_t)b * T_ + t0) * C_ + c0);
    float s[4] = {0.f, 0.f, 0.f, 0.f};
    #pragma unroll 8
    for (int i = 0; i < TB; ++i) {
        const float4 xv = xp[(size_t)i * (C_ >> 2)];
        const bool z0 = (t0 + i) == 0;
        s[0] = fmaf(xv.x, z0 ? 1.0f : ap[0] * oma[0], s[0]);
        s[1] = fmaf(xv.y, z0 ? 1.0f : ap[1] * oma[1], s[1]);
        s[2] = fmaf(xv.z, z0 ? 1.0f : ap[2] * oma[2], s[2]);
        s[3] = fmaf(xv.w, z0 ? 1.0f : ap[3] * oma[3], s[3]);
        #pragma unroll
        for (int j = 0; j < 4; ++j) ap[j] *= a[j];
    }
    *(float4*)(ws + (size_t)(b * NTB + tb) * C_ + c0) =
        make_float4(s[0], s[1], s[2], s[3]);
}

// 16384 threads; thread g owns column (b = g>>9, c = g&511) of ws,
// exclusive scan over the 64 chunks in place.
__global__ __launch_bounds__(256, 4)
void ema_scanws(float* __restrict__ ws) {
    const int g = blockIdx.x * 256 + threadIdx.x;
    const int b = g >> 9, c = g & (C_ - 1);
    float* __restrict__ p = ws + (size_t)b * NTB * C_ + c;
    float v[NTB];
    #pragma unroll
    for (int k = 0; k < NTB; ++k) v[k] = p[(size_t)k * C_];   // 64 indep loads
    float run = 0.0f;
    #pragma unroll
    for (int k = 0; k < NTB; ++k) {
        p[(size_t)k * C_] = run;
        run += v[k];
    }
}

__global__ __launch_bounds__(256, 4)
void ema_apply(const float* __restrict__ x,
               const float* __restrict__ la,
               const float* __restrict__ ws,
               float* __restrict__ y) {
    const int tid = threadIdx.x;
    const int ct  = tid & 127;
    const int cs  = tid >> 7;
    const int b   = blockIdx.x >> 5;
    const int pr  = blockIdx.x & 31;
    const int tb  = (pr << 1) | cs;
    const int c0  = ct << 2;
    const int t0  = tb * TB;

    const float4 z4 = *(const float4*)(la + c0);
    const float zz[4] = {z4.x, z4.y, z4.z, z4.w};
    float a[4], oma[4], ap[4], inva[4], invap[4];
    #pragma unroll
    for (int j = 0; j < 4; ++j) {
        a[j]     = clamp_sig(zz[j]);
        oma[j]   = 1.0f - a[j];
        const float l2a = log2f(a[j]);
        ap[j]    = exp2f((float)t0 * l2a);
        invap[j] = exp2f(-(float)t0 * l2a);  // inf ok: clamped to 1e8 below
        inva[j]  = 1.0f / a[j];
    }

    // exclusive prefix: ONE float4 read (K2 already did the scan)
    const float4 p0 = *(const float4*)(ws + (size_t)(b * NTB + tb) * C_ + c0);
    float S[4] = {p0.x, p0.y, p0.z, p0.w};

    const float4* __restrict__ xp =
        (const float4*)(x + ((size_t)b * T_ + t0) * C_ + c0);
    float* __restrict__ yp = y + ((size_t)b * T_ + t0) * C_ + c0;

    #pragma unroll 4
    for (int i = 0; i < TB; ++i) {
        const float4 xv = xp[(size_t)i * (C_ >> 2)];
        const bool z0 = (t0 + i) == 0;
        S[0] = fmaf(xv.x, z0 ? 1.0f : ap[0] * oma[0], S[0]);
        S[1] = fmaf(xv.y, z0 ? 1.0f : ap[1] * oma[1], S[1]);
        S[2] = fmaf(xv.z, z0 ? 1.0f : ap[2] * oma[2], S[2]);
        S[3] = fmaf(xv.w, z0 ? 1.0f : ap[3] * oma[3], S[3]);
        // 1/max(a^t,1e-8) == min(a^-t, 1e8); inf clamps to 1e8 (matches EPS)
        f32x4 out;
        out.x = S[0] * fminf(invap[0], 1e8f);
        out.y = S[1] * fminf(invap[1], 1e8f);
        out.z = S[2] * fminf(invap[2], 1e8f);
        out.w = S[3] * fminf(invap[3], 1e8f);
        __builtin_nontemporal_store(out, (f32x4*)(yp + (size_t)i * C_));
        #pragma unroll
        for (int j = 0; j < 4; ++j) { ap[j] *= a[j]; invap[j] *= inva[j]; }
    }
}

extern "C" void kernel_launch(void* const* d_in, const int* in_sizes, int n_in,
                              void* d_out, int out_size, void* d_ws, size_t ws_size,
                              hipStream_t stream) {
    const float* x  = (const float*)d_in[0];   // [32, 2048, 512] fp32
    const float* la = (const float*)d_in[1];   // [512] fp32
    float* y  = (float*)d_out;                 // [32, 2048, 512] fp32
    float* ws = (float*)d_ws;                  // B*NTB*C*4 = 4 MB

    hipLaunchKernelGGL(ema_partials, dim3(B_ * (NTB / 2)), dim3(256), 0, stream,
                       x, la, ws);
    hipLaunchKernelGGL(ema_scanws,   dim3(B_ * C_ / 256),  dim3(256), 0, stream,
                       ws);
    hipLaunchKernelGGL(ema_apply,    dim3(B_ * (NTB / 2)), dim3(256), 0, stream,
                       x, la, ws, y);
}